// Round 2
// 374.234 us; speedup vs baseline: 1.1224x; 1.1224x over previous
//
#include <hip/hip_runtime.h>

typedef unsigned short ushortT;
typedef unsigned int uintT;
typedef __attribute__((ext_vector_type(8))) short short8;
typedef __attribute__((ext_vector_type(4))) short short4v;
typedef __attribute__((ext_vector_type(4))) float float4v;

// Problem constants
constexpr int B  = 16;
constexpr int C  = 512;
constexpr int CC = 64;      // c = C/8
constexpr int N  = 4096;    // H*W

// Workspace layout (float units)
constexpr size_t QK_OFF  = 0;
constexpr size_t S_OFF   = 8388608;
constexpr size_t VT_OFF  = 8454144;
constexpr size_t MF_OFF  = 10551296;
constexpr size_t WH_OFF  = 10813440;
constexpr size_t WL_OFF  = 10862592;
constexpr size_t WOT_OFF = 10911744;

// async global->LDS, 16B per lane; LDS dest = wave-uniform base + lane*16
#define GLL(lds, g) __builtin_amdgcn_global_load_lds( \
    (const __attribute__((address_space(1))) void*)(g), \
    (__attribute__((address_space(3))) void*)(lds), 16, 0, 0)

static __device__ __forceinline__ ushortT f2bf(float f) {
    uintT u = __float_as_uint(f);
    u = (u + 0x7fffu + ((u >> 16) & 1u)) >> 16;   // RNE
    return (ushortT)u;
}
static __device__ __forceinline__ float bf2f(ushortT h) {
    return __uint_as_float(((uintT)h) << 16);
}

// ---------------------------------------------------------------------------
// Weight prep: split W into bf16 hi/lo, laid out [ktile][192 rows][64 k] with
// per-row XOR chunk swizzle (16B chunk c stored at c ^ (row&7)).
// Also wot[cc][co] = Wo[co][cc] fp32 for the softmax-fold kernel.
__global__ __launch_bounds__(256) void k_prep_w(
    const float* __restrict__ Wq, const float* __restrict__ Wk,
    const float* __restrict__ Wv, const float* __restrict__ Wo,
    ushortT* __restrict__ wh, ushortT* __restrict__ wl, float* __restrict__ wot)
{
    int idx = blockIdx.x * 256 + threadIdx.x;   // 0..131071
    if (idx < 3 * CC * C) {                     // 98304
        int m = idx >> 9, k = idx & 511;        // m 0..191
        const float* W = (m < 64) ? Wq : (m < 128 ? Wk : Wv);
        float v = W[(m & 63) * C + k];
        ushortT h = f2bf(v);
        ushortT l = f2bf(v - bf2f(h));
        int kt = k >> 6, kk = k & 63;
        size_t off = ((size_t)(kt * 192 + m)) * 64 + (size_t)(((kk >> 3) ^ (m & 7)) * 8) + (kk & 7);
        wh[off] = h;
        wl[off] = l;
    } else {
        int i2 = idx - 3 * CC * C;              // cc*512 + co
        int cc = i2 >> 9, co = i2 & 511;
        wot[i2] = Wo[co * CC + cc];
    }
}

// ---------------------------------------------------------------------------
// QKV projection, split-bf16 MFMA:  D = Wh*Xh + Wl*Xh + Wh*Xl  (fp32 acc).
// Pipelined: both Wh/Wl of a k-tile resident in LDS (one merged 72-MFMA phase,
// 2 barriers/kt), X slab prefetched into registers one k-tile ahead, B buffers
// double-buffered, staging writes are swizzled ds_write_b128 (conflict-free).
__global__ __launch_bounds__(256) void k_qkv(
    const float* __restrict__ x,
    const ushortT* __restrict__ wh, const ushortT* __restrict__ wl,
    const float* __restrict__ bq, const float* __restrict__ bk,
    const float* __restrict__ bv,
    float* __restrict__ qk, ushortT* __restrict__ vt)
{
    __shared__ ushortT Ah[192 * 64];      // 24 KB  (Wh tile, swizzled rows)
    __shared__ ushortT Al[192 * 64];      // 24 KB  (Wl tile)
    __shared__ ushortT Bh[2][64 * 64];    // 16 KB  (x hi, [n][k] swizzled, dbuf)
    __shared__ ushortT Bl[2][64 * 64];    // 16 KB  (x lo)

    const int tid  = threadIdx.x;
    const int n0   = blockIdx.x * 64;     // 64 col-tiles
    const int b    = blockIdx.y;
    const int lane = tid & 63;
    const int wv   = tid >> 6;            // 4 waves, wave tile 48m x 64n
    const int L15  = lane & 15, Lq = lane >> 4;

    // staging assignment: thread covers column nl, k-groups kg0 and kg0+4
    const int nl  = tid & 63;
    const int kg0 = tid >> 6;             // 0..3

    const float* xb = x + (size_t)b * C * N + n0 + nl;

    float xr[2][8];
    float4v acc[3][4];
    const float4v vzero = {0.f, 0.f, 0.f, 0.f};
#pragma unroll
    for (int mi = 0; mi < 3; ++mi)
#pragma unroll
        for (int ni = 0; ni < 4; ++ni) acc[mi][ni] = vzero;

    // ---- prologue: load x(kt0) -> regs, convert -> B[0], GLL weights(kt0) ----
#pragma unroll
    for (int u = 0; u < 2; ++u) {
        const int kg = kg0 + 4 * u;
#pragma unroll
        for (int j = 0; j < 8; ++j)
            xr[u][j] = xb[(size_t)(kg * 8 + j) * N];
    }
    {
        const char* srcH = (const char*)wh;
        const char* srcL = (const char*)wl;
#pragma unroll
        for (int i = 0; i < 6; ++i) {
            int off = i * 4096 + tid * 16;
            GLL((char*)Ah + off, srcH + off);
            GLL((char*)Al + off, srcL + off);
        }
    }
#pragma unroll
    for (int u = 0; u < 2; ++u) {
        const int kg = kg0 + 4 * u;
        short8 h8, l8;
#pragma unroll
        for (int j = 0; j < 8; ++j) {
            float v = xr[u][j];
            ushortT h = f2bf(v);
            h8[j] = (short)h;
            l8[j] = (short)f2bf(v - bf2f(h));
        }
        int idx = nl * 64 + (kg ^ (nl & 7)) * 8;
        *(short8*)&Bh[0][idx] = h8;
        *(short8*)&Bl[0][idx] = l8;
    }
    __syncthreads();

    for (int kt = 0; kt < 8; ++kt) {
        const int cur = kt & 1;
        // ---- issue x loads for kt+1 (latency hides under MFMA phase) ----
        if (kt < 7) {
#pragma unroll
            for (int u = 0; u < 2; ++u) {
                const int kg = kg0 + 4 * u;
#pragma unroll
                for (int j = 0; j < 8; ++j)
                    xr[u][j] = xb[(size_t)((kt + 1) * 64 + kg * 8 + j) * N];
            }
        }
        // ---- merged MFMA phase: Wh*Xh + Wl*Xh + Wh*Xl (72 MFMA/wave) ----
#pragma unroll
        for (int s = 0; s < 2; ++s) {
            short8 fbh[4], fbl[4];
#pragma unroll
            for (int ni = 0; ni < 4; ++ni) {
                int row = ni * 16 + L15;
                int off = row * 64 + ((4 * s + Lq) ^ (row & 7)) * 8;
                fbh[ni] = *(const short8*)&Bh[cur][off];
                fbl[ni] = *(const short8*)&Bl[cur][off];
            }
#pragma unroll
            for (int mi = 0; mi < 3; ++mi) {
                int rm = 48 * wv + mi * 16 + L15;
                int aoff = rm * 64 + ((4 * s + Lq) ^ (rm & 7)) * 8;
                short8 ah = *(const short8*)&Ah[aoff];
                short8 al = *(const short8*)&Al[aoff];
#pragma unroll
                for (int ni = 0; ni < 4; ++ni)
                    acc[mi][ni] = __builtin_amdgcn_mfma_f32_16x16x32_bf16(ah, fbh[ni], acc[mi][ni], 0, 0, 0);
#pragma unroll
                for (int ni = 0; ni < 4; ++ni)
                    acc[mi][ni] = __builtin_amdgcn_mfma_f32_16x16x32_bf16(al, fbh[ni], acc[mi][ni], 0, 0, 0);
#pragma unroll
                for (int ni = 0; ni < 4; ++ni)
                    acc[mi][ni] = __builtin_amdgcn_mfma_f32_16x16x32_bf16(ah, fbl[ni], acc[mi][ni], 0, 0, 0);
            }
        }
        __syncthreads();   // all waves done reading Ah/Al and B[cur]
        if (kt < 7) {
            // ---- GLL weights(kt+1); convert x regs -> B[cur^1] under its latency ----
            const char* srcH = (const char*)wh + (size_t)(kt + 1) * 24576;
            const char* srcL = (const char*)wl + (size_t)(kt + 1) * 24576;
#pragma unroll
            for (int i = 0; i < 6; ++i) {
                int off = i * 4096 + tid * 16;
                GLL((char*)Ah + off, srcH + off);
                GLL((char*)Al + off, srcL + off);
            }
            const int nxt = cur ^ 1;
#pragma unroll
            for (int u = 0; u < 2; ++u) {
                const int kg = kg0 + 4 * u;
                short8 h8, l8;
#pragma unroll
                for (int j = 0; j < 8; ++j) {
                    float v = xr[u][j];
                    ushortT h = f2bf(v);
                    h8[j] = (short)h;
                    l8[j] = (short)f2bf(v - bf2f(h));
                }
                int idx = nl * 64 + (kg ^ (nl & 7)) * 8;
                *(short8*)&Bh[nxt][idx] = h8;
                *(short8*)&Bl[nxt][idx] = l8;
            }
            __syncthreads();   // GLL drained (vmcnt) + B writes visible
        }
    }

    // ---- epilogue: rows 0-63 -> Q (fp32), 64-127 -> K (fp32), 128-191 -> V ----
#pragma unroll
    for (int mi = 0; mi < 3; ++mi) {
        int rbase = 48 * wv + mi * 16;     // 16-aligned, frag fits one 64-block
        int type = rbase >> 6;             // 0=Q 1=K 2=V (uniform per frag)
#pragma unroll
        for (int ni = 0; ni < 4; ++ni) {
            int col = n0 + ni * 16 + L15;
            float4v v4 = acc[mi][ni];
            if (type == 0) {
#pragma unroll
                for (int reg = 0; reg < 4; ++reg) {
                    int rl = (rbase + Lq * 4 + reg) & 63;
                    qk[((size_t)(b * 64 + rl)) * N + col] = v4[reg] + bq[rl];
                }
            } else if (type == 1) {
#pragma unroll
                for (int reg = 0; reg < 4; ++reg) {
                    int rl = (rbase + Lq * 4 + reg) & 63;
                    qk[((size_t)((16 + b) * 64 + rl)) * N + col] = v4[reg] + bk[rl];
                }
            } else {
                int rl0 = (rbase + Lq * 4) & 63;   // 4-aligned, (rl0>>3) const over regs
                short4v p;
#pragma unroll
                for (int reg = 0; reg < 4; ++reg)
                    p[reg] = (short)f2bf(v4[reg] + bv[rl0 + reg]);
                size_t off = ((size_t)(b * N + col)) * 64 + (size_t)(((rl0 >> 3) ^ (col & 7)) * 8) + (rl0 & 7);
                *(short4v*)&vt[off] = p;           // 8B packed store
            }
        }
    }
}

// ---------------------------------------------------------------------------
// Logits: S[b] += Q[b][:, n0:n0+64] @ Kresh[n0:n0+64, :]  (split-K atomics).
// Kresh[n, j] = Kflat[b, n*64 + j]  (the torch .view reshape, NOT a transpose).
// Each block accumulates 4 n-chunks in registers -> 4x fewer atomics.
__global__ __launch_bounds__(256) void k_logits(
    const float* __restrict__ qk, float* __restrict__ S)
{
    int b = blockIdx.x;        // 16
    __shared__ float Qs[64 * 68];
    __shared__ float Ks[64 * 64];

    const float* Qb = qk + (size_t)b * (CC * N);
    const float* Kb = qk + (size_t)(16 + b) * (CC * N);
    int tid = threadIdx.x;
    int ti = tid >> 4, tj = tid & 15;
    int i0 = ti * 4, j0 = tj * 4;
    float accl[4][4] = {};

    for (int ci = 0; ci < 4; ++ci) {
        int n0 = (blockIdx.y * 4 + ci) * 64;
        if (ci) __syncthreads();           // previous compute done before restage
        for (int t = tid; t < 1024; t += 256) {
            int i = t >> 4, c4 = (t & 15) * 4;
            *(float4*)&Qs[i * 68 + c4] = *(const float4*)&Qb[(size_t)i * N + n0 + c4];
            *(float4*)&Ks[t * 4]       = *(const float4*)&Kb[(size_t)n0 * 64 + t * 4];
        }
        __syncthreads();
        for (int nn = 0; nn < 64; ++nn) {
            float4 kv = *reinterpret_cast<const float4*>(&Ks[nn * 64 + j0]);
            float qa[4];
#pragma unroll
            for (int a = 0; a < 4; ++a) qa[a] = Qs[(i0 + a) * 68 + nn];
#pragma unroll
            for (int a = 0; a < 4; ++a) {
                accl[a][0] = fmaf(qa[a], kv.x, accl[a][0]);
                accl[a][1] = fmaf(qa[a], kv.y, accl[a][1]);
                accl[a][2] = fmaf(qa[a], kv.z, accl[a][2]);
                accl[a][3] = fmaf(qa[a], kv.w, accl[a][3]);
            }
        }
    }
    float* Sb = S + b * (CC * CC);
#pragma unroll
    for (int a = 0; a < 4; ++a)
#pragma unroll
        for (int bb = 0; bb < 4; ++bb)
            atomicAdd(&Sb[(i0 + a) * 64 + j0 + bb], accl[a][bb]);
}

// ---------------------------------------------------------------------------
// Softmax over rows of S[b] (64x64), then fold Wo:
//   Mf[b][co][e] = sum_c Wo[co,c] * attn[c,e]  -> bf16, swizzled rows of 128B.
__global__ __launch_bounds__(256) void k_softmax_m(
    const float* __restrict__ S, const float* __restrict__ wot,
    ushortT* __restrict__ mf)
{
    int b = blockIdx.x, chunk = blockIdx.y;   // 16 x 8
    __shared__ float A[64 * 65];
    int tid = threadIdx.x;
    const float* Sb = S + b * (CC * CC);

    for (int t = tid; t < 4096; t += 256) A[(t >> 6) * 65 + (t & 63)] = Sb[t];
    __syncthreads();
    if (tid < 64) {
        float mx = -1e30f;
        for (int j = 0; j < 64; ++j) mx = fmaxf(mx, A[tid * 65 + j]);
        float sum = 0.f;
        for (int j = 0; j < 64; ++j) {
            float e = __expf(A[tid * 65 + j] - mx);
            A[tid * 65 + j] = e;
            sum += e;
        }
        float inv = 1.f / sum;
        for (int j = 0; j < 64; ++j) A[tid * 65 + j] *= inv;
    }
    __syncthreads();

    int co = chunk * 64 + (tid & 63);
    int e0 = (tid >> 6) * 16;
    float acc[16] = {};
    for (int cc = 0; cc < 64; ++cc) {
        float w = wot[cc * C + co];
#pragma unroll
        for (int ee = 0; ee < 16; ++ee)
            acc[ee] = fmaf(w, A[cc * 65 + e0 + ee], acc[ee]);
    }
#pragma unroll
    for (int d = 0; d < 2; ++d) {
        int c = (e0 >> 3) + d;               // logical 8-elem chunk
        uintT p0 = (uintT)f2bf(acc[d * 8 + 0]) | ((uintT)f2bf(acc[d * 8 + 1]) << 16);
        uintT p1 = (uintT)f2bf(acc[d * 8 + 2]) | ((uintT)f2bf(acc[d * 8 + 3]) << 16);
        uintT p2 = (uintT)f2bf(acc[d * 8 + 4]) | ((uintT)f2bf(acc[d * 8 + 5]) << 16);
        uintT p3 = (uintT)f2bf(acc[d * 8 + 6]) | ((uintT)f2bf(acc[d * 8 + 7]) << 16);
        uint4 pk = make_uint4(p0, p1, p2, p3);
        size_t off = ((size_t)(b * C + co)) * 64 + (size_t)((c ^ (co & 7)) * 8);
        *(uint4*)&mf[off] = pk;
    }
}

// ---------------------------------------------------------------------------
// Output: out[b,co,n] = gamma*( sum_e Mf[co,e]*Vt[n,e] + bo[co] ) + x[b,co,n]
// MFMA with swapped operands: A-frag = Vt rows (n), B-frag = Mf rows (co).
// D rows = n -> each lane's 4 acc regs are 4 CONSECUTIVE n -> float4 epilogue.
__global__ __launch_bounds__(256) void k_out(
    const ushortT* __restrict__ vt, const ushortT* __restrict__ mf,
    const float* __restrict__ x, const float* __restrict__ bo,
    const float* __restrict__ gamma, float* __restrict__ out)
{
    __shared__ ushortT As[64 * 64];    // 8 KB  Mf rows co0..co0+64
    __shared__ ushortT Bs[256 * 64];   // 32 KB Vt rows n0..n0+256

    int b = blockIdx.x, ct = blockIdx.y, nt = blockIdx.z;
    int co0 = ct * 64, n0 = nt * 256;
    int tid = threadIdx.x;
    const char* asrc = (const char*)mf + ((size_t)(b * C + co0)) * 128;
    const char* bsrc = (const char*)vt + ((size_t)(b * N + n0)) * 128;
#pragma unroll
    for (int i = 0; i < 2; ++i) {
        int off = i * 4096 + tid * 16;
        GLL((char*)As + off, asrc + off);
    }
#pragma unroll
    for (int i = 0; i < 8; ++i) {
        int off = i * 4096 + tid * 16;
        GLL((char*)Bs + off, bsrc + off);
    }
    __syncthreads();

    int lane = tid & 63, wv = tid >> 6;
    int L15 = lane & 15, Lq = lane >> 4;
    float4v acc[4][4];                 // [n-frag][co-frag]
    const float4v vzero = {0.f, 0.f, 0.f, 0.f};
#pragma unroll
    for (int mi = 0; mi < 4; ++mi)
#pragma unroll
        for (int ni = 0; ni < 4; ++ni) acc[mi][ni] = vzero;

#pragma unroll
    for (int s = 0; s < 2; ++s) {
        short8 fa[4], fbm[4];
#pragma unroll
        for (int mi = 0; mi < 4; ++mi) {         // Vt frags (n rows)
            int row = wv * 64 + mi * 16 + L15;
            fa[mi] = *(const short8*)&Bs[row * 64 + ((4 * s + Lq) ^ (row & 7)) * 8];
        }
#pragma unroll
        for (int ni = 0; ni < 4; ++ni) {         // Mf frags (co rows)
            int rm = ni * 16 + L15;
            fbm[ni] = *(const short8*)&As[rm * 64 + ((4 * s + Lq) ^ (rm & 7)) * 8];
        }
#pragma unroll
        for (int mi = 0; mi < 4; ++mi)
#pragma unroll
            for (int ni = 0; ni < 4; ++ni)
                acc[mi][ni] = __builtin_amdgcn_mfma_f32_16x16x32_bf16(fa[mi], fbm[ni], acc[mi][ni], 0, 0, 0);
    }

    float g = gamma[0];
#pragma unroll
    for (int ni = 0; ni < 4; ++ni) {
        int co = co0 + ni * 16 + L15;
        float bov = bo[co];
#pragma unroll
        for (int mi = 0; mi < 4; ++mi) {
            int nbase = n0 + wv * 64 + mi * 16 + Lq * 4;
            size_t idx = ((size_t)(b * C + co)) * N + nbase;
            float4 xv = *(const float4*)&x[idx];
            float4v v4 = acc[mi][ni];
            float4 o;
            o.x = fmaf(g, v4[0] + bov, xv.x);
            o.y = fmaf(g, v4[1] + bov, xv.y);
            o.z = fmaf(g, v4[2] + bov, xv.z);
            o.w = fmaf(g, v4[3] + bov, xv.w);
            *(float4*)&out[idx] = o;
        }
    }
}

// ---------------------------------------------------------------------------
extern "C" void kernel_launch(void* const* d_in, const int* in_sizes, int n_in,
                              void* d_out, int out_size, void* d_ws, size_t ws_size,
                              hipStream_t stream)
{
    const float* x     = (const float*)d_in[0];
    const float* Wq    = (const float*)d_in[1];
    const float* bq    = (const float*)d_in[2];
    const float* Wk    = (const float*)d_in[3];
    const float* bk    = (const float*)d_in[4];
    const float* Wv    = (const float*)d_in[5];
    const float* bv    = (const float*)d_in[6];
    const float* Wo    = (const float*)d_in[7];
    const float* bo    = (const float*)d_in[8];
    const float* gamma = (const float*)d_in[9];

    float* ws   = (float*)d_ws;
    float* qk   = ws + QK_OFF;
    float* S    = ws + S_OFF;
    ushortT* vt = (ushortT*)(ws + VT_OFF);
    ushortT* mf = (ushortT*)(ws + MF_OFF);
    ushortT* wh = (ushortT*)(ws + WH_OFF);
    ushortT* wl = (ushortT*)(ws + WL_OFF);
    float* wot  = ws + WOT_OFF;

    hipMemsetAsync(S, 0, (size_t)B * CC * CC * sizeof(float), stream);
    k_prep_w<<<512, 256, 0, stream>>>(Wq, Wk, Wv, Wo, wh, wl, wot);
    k_qkv<<<dim3(64, 16), 256, 0, stream>>>(x, wh, wl, bq, bk, bv, qk, vt);
    k_logits<<<dim3(16, 16), 256, 0, stream>>>(qk, S);
    k_softmax_m<<<dim3(16, 8), 256, 0, stream>>>(S, wot, mf);
    k_out<<<dim3(16, 8, 16), 256, 0, stream>>>(vt, mf, x, bo, gamma, (float*)d_out);
}

// Round 3
// 355.706 us; speedup vs baseline: 1.1808x; 1.0521x over previous
//
#include <hip/hip_runtime.h>

typedef unsigned short ushortT;
typedef unsigned int uintT;
typedef __attribute__((ext_vector_type(8))) short short8;
typedef __attribute__((ext_vector_type(4))) short short4v;
typedef __attribute__((ext_vector_type(4))) float float4v;

// Problem constants
constexpr int B  = 16;
constexpr int C  = 512;
constexpr int CC = 64;      // c = C/8
constexpr int N  = 4096;    // H*W

// Workspace layout (float units)
constexpr size_t QK_OFF  = 0;
constexpr size_t S_OFF   = 8388608;   // (unused now, kept for layout stability)
constexpr size_t VT_OFF  = 8454144;
constexpr size_t MF_OFF  = 10551296;
constexpr size_t WH_OFF  = 10813440;
constexpr size_t WL_OFF  = 10862592;
constexpr size_t WOT_OFF = 10911744;
constexpr size_t SP_OFF  = 10944512;  // 32 partials x 16 b x 64 x 64 = 2,097,152 fl (8 MB)

// async global->LDS, 16B per lane; LDS dest = wave-uniform base + lane*16
#define GLL(lds, g) __builtin_amdgcn_global_load_lds( \
    (const __attribute__((address_space(1))) void*)(g), \
    (__attribute__((address_space(3))) void*)(lds), 16, 0, 0)

static __device__ __forceinline__ ushortT f2bf(float f) {
    uintT u = __float_as_uint(f);
    u = (u + 0x7fffu + ((u >> 16) & 1u)) >> 16;   // RNE
    return (ushortT)u;
}
static __device__ __forceinline__ float bf2f(ushortT h) {
    return __uint_as_float(((uintT)h) << 16);
}

// ---------------------------------------------------------------------------
// Weight prep: split W into bf16 hi/lo, laid out [ktile][192 rows][64 k] with
// per-row XOR chunk swizzle (16B chunk c stored at c ^ (row&7)).
// Also wot[cc][co] = Wo[co][cc] fp32 for the softmax-fold kernel.
__global__ __launch_bounds__(256) void k_prep_w(
    const float* __restrict__ Wq, const float* __restrict__ Wk,
    const float* __restrict__ Wv, const float* __restrict__ Wo,
    ushortT* __restrict__ wh, ushortT* __restrict__ wl, float* __restrict__ wot)
{
    int idx = blockIdx.x * 256 + threadIdx.x;   // 0..131071
    if (idx < 3 * CC * C) {                     // 98304
        int m = idx >> 9, k = idx & 511;        // m 0..191
        const float* W = (m < 64) ? Wq : (m < 128 ? Wk : Wv);
        float v = W[(m & 63) * C + k];
        ushortT h = f2bf(v);
        ushortT l = f2bf(v - bf2f(h));
        int kt = k >> 6, kk = k & 63;
        size_t off = ((size_t)(kt * 192 + m)) * 64 + (size_t)(((kk >> 3) ^ (m & 7)) * 8) + (kk & 7);
        wh[off] = h;
        wl[off] = l;
    } else {
        int i2 = idx - 3 * CC * C;              // cc*512 + co
        int cc = i2 >> 9, co = i2 & 511;
        wot[i2] = Wo[co * CC + cc];
    }
}

// ---------------------------------------------------------------------------
// QKV projection, split-bf16 MFMA:  D = Wh*Xh + Wl*Xh + Wh*Xl  (fp32 acc).
// Pipelined: both Wh/Wl of a k-tile resident in LDS (one merged 72-MFMA phase,
// 2 barriers/kt), X slab prefetched into registers one k-tile ahead, B buffers
// double-buffered, staging writes are swizzled ds_write_b128 (conflict-free).
__global__ __launch_bounds__(256) void k_qkv(
    const float* __restrict__ x,
    const ushortT* __restrict__ wh, const ushortT* __restrict__ wl,
    const float* __restrict__ bq, const float* __restrict__ bk,
    const float* __restrict__ bv,
    float* __restrict__ qk, ushortT* __restrict__ vt)
{
    __shared__ ushortT Ah[192 * 64];      // 24 KB  (Wh tile, swizzled rows)
    __shared__ ushortT Al[192 * 64];      // 24 KB  (Wl tile)
    __shared__ ushortT Bh[2][64 * 64];    // 16 KB  (x hi, [n][k] swizzled, dbuf)
    __shared__ ushortT Bl[2][64 * 64];    // 16 KB  (x lo)

    const int tid  = threadIdx.x;
    const int n0   = blockIdx.x * 64;     // 64 col-tiles
    const int b    = blockIdx.y;
    const int lane = tid & 63;
    const int wv   = tid >> 6;            // 4 waves, wave tile 48m x 64n
    const int L15  = lane & 15, Lq = lane >> 4;

    // staging assignment: thread covers column nl, k-groups kg0 and kg0+4
    const int nl  = tid & 63;
    const int kg0 = tid >> 6;             // 0..3

    const float* xb = x + (size_t)b * C * N + n0 + nl;

    float xr[2][8];
    float4v acc[3][4];
    const float4v vzero = {0.f, 0.f, 0.f, 0.f};
#pragma unroll
    for (int mi = 0; mi < 3; ++mi)
#pragma unroll
        for (int ni = 0; ni < 4; ++ni) acc[mi][ni] = vzero;

    // ---- prologue: load x(kt0) -> regs, convert -> B[0], GLL weights(kt0) ----
#pragma unroll
    for (int u = 0; u < 2; ++u) {
        const int kg = kg0 + 4 * u;
#pragma unroll
        for (int j = 0; j < 8; ++j)
            xr[u][j] = xb[(size_t)(kg * 8 + j) * N];
    }
    {
        const char* srcH = (const char*)wh;
        const char* srcL = (const char*)wl;
#pragma unroll
        for (int i = 0; i < 6; ++i) {
            int off = i * 4096 + tid * 16;
            GLL((char*)Ah + off, srcH + off);
            GLL((char*)Al + off, srcL + off);
        }
    }
#pragma unroll
    for (int u = 0; u < 2; ++u) {
        const int kg = kg0 + 4 * u;
        short8 h8, l8;
#pragma unroll
        for (int j = 0; j < 8; ++j) {
            float v = xr[u][j];
            ushortT h = f2bf(v);
            h8[j] = (short)h;
            l8[j] = (short)f2bf(v - bf2f(h));
        }
        int idx = nl * 64 + (kg ^ (nl & 7)) * 8;
        *(short8*)&Bh[0][idx] = h8;
        *(short8*)&Bl[0][idx] = l8;
    }
    __syncthreads();

    for (int kt = 0; kt < 8; ++kt) {
        const int cur = kt & 1;
        // ---- issue x loads for kt+1 (latency hides under MFMA phase) ----
        if (kt < 7) {
#pragma unroll
            for (int u = 0; u < 2; ++u) {
                const int kg = kg0 + 4 * u;
#pragma unroll
                for (int j = 0; j < 8; ++j)
                    xr[u][j] = xb[(size_t)((kt + 1) * 64 + kg * 8 + j) * N];
            }
        }
        // ---- merged MFMA phase: Wh*Xh + Wl*Xh + Wh*Xl (72 MFMA/wave) ----
#pragma unroll
        for (int s = 0; s < 2; ++s) {
            short8 fbh[4], fbl[4];
#pragma unroll
            for (int ni = 0; ni < 4; ++ni) {
                int row = ni * 16 + L15;
                int off = row * 64 + ((4 * s + Lq) ^ (row & 7)) * 8;
                fbh[ni] = *(const short8*)&Bh[cur][off];
                fbl[ni] = *(const short8*)&Bl[cur][off];
            }
#pragma unroll
            for (int mi = 0; mi < 3; ++mi) {
                int rm = 48 * wv + mi * 16 + L15;
                int aoff = rm * 64 + ((4 * s + Lq) ^ (rm & 7)) * 8;
                short8 ah = *(const short8*)&Ah[aoff];
                short8 al = *(const short8*)&Al[aoff];
#pragma unroll
                for (int ni = 0; ni < 4; ++ni)
                    acc[mi][ni] = __builtin_amdgcn_mfma_f32_16x16x32_bf16(ah, fbh[ni], acc[mi][ni], 0, 0, 0);
#pragma unroll
                for (int ni = 0; ni < 4; ++ni)
                    acc[mi][ni] = __builtin_amdgcn_mfma_f32_16x16x32_bf16(al, fbh[ni], acc[mi][ni], 0, 0, 0);
#pragma unroll
                for (int ni = 0; ni < 4; ++ni)
                    acc[mi][ni] = __builtin_amdgcn_mfma_f32_16x16x32_bf16(ah, fbl[ni], acc[mi][ni], 0, 0, 0);
            }
        }
        __syncthreads();   // all waves done reading Ah/Al and B[cur]
        if (kt < 7) {
            // ---- GLL weights(kt+1); convert x regs -> B[cur^1] under its latency ----
            const char* srcH = (const char*)wh + (size_t)(kt + 1) * 24576;
            const char* srcL = (const char*)wl + (size_t)(kt + 1) * 24576;
#pragma unroll
            for (int i = 0; i < 6; ++i) {
                int off = i * 4096 + tid * 16;
                GLL((char*)Ah + off, srcH + off);
                GLL((char*)Al + off, srcL + off);
            }
            const int nxt = cur ^ 1;
#pragma unroll
            for (int u = 0; u < 2; ++u) {
                const int kg = kg0 + 4 * u;
                short8 h8, l8;
#pragma unroll
                for (int j = 0; j < 8; ++j) {
                    float v = xr[u][j];
                    ushortT h = f2bf(v);
                    h8[j] = (short)h;
                    l8[j] = (short)f2bf(v - bf2f(h));
                }
                int idx = nl * 64 + (kg ^ (nl & 7)) * 8;
                *(short8*)&Bh[nxt][idx] = h8;
                *(short8*)&Bl[nxt][idx] = l8;
            }
            __syncthreads();   // GLL drained (vmcnt) + B writes visible
        }
    }

    // ---- epilogue: rows 0-63 -> Q (fp32), 64-127 -> K (fp32), 128-191 -> V ----
#pragma unroll
    for (int mi = 0; mi < 3; ++mi) {
        int rbase = 48 * wv + mi * 16;     // 16-aligned, frag fits one 64-block
        int type = rbase >> 6;             // 0=Q 1=K 2=V (uniform per frag)
#pragma unroll
        for (int ni = 0; ni < 4; ++ni) {
            int col = n0 + ni * 16 + L15;
            float4v v4 = acc[mi][ni];
            if (type == 0) {
#pragma unroll
                for (int reg = 0; reg < 4; ++reg) {
                    int rl = (rbase + Lq * 4 + reg) & 63;
                    qk[((size_t)(b * 64 + rl)) * N + col] = v4[reg] + bq[rl];
                }
            } else if (type == 1) {
#pragma unroll
                for (int reg = 0; reg < 4; ++reg) {
                    int rl = (rbase + Lq * 4 + reg) & 63;
                    qk[((size_t)((16 + b) * 64 + rl)) * N + col] = v4[reg] + bk[rl];
                }
            } else {
                int rl0 = (rbase + Lq * 4) & 63;   // 4-aligned, (rl0>>3) const over regs
                short4v p;
#pragma unroll
                for (int reg = 0; reg < 4; ++reg)
                    p[reg] = (short)f2bf(v4[reg] + bv[rl0 + reg]);
                size_t off = ((size_t)(b * N + col)) * 64 + (size_t)(((rl0 >> 3) ^ (col & 7)) * 8) + (rl0 & 7);
                *(short4v*)&vt[off] = p;           // 8B packed store
            }
        }
    }
}

// ---------------------------------------------------------------------------
// Logits partials: Sp[part][b] = sum over 2 n-chunks of Q[b] @ Kresh chunk.
// Kresh[n, j] = Kflat[b, n*64 + j]  (the torch .view reshape, NOT a transpose).
// NO atomics: each (b, part) block writes its own 64x64 fp32 partial tile;
// k_softmax_m reduces the 32 partials (L2-hot). Grid 16 x 32 -> 2 blocks/CU.
__global__ __launch_bounds__(256) void k_logits(
    const float* __restrict__ qk, float* __restrict__ Sp)
{
    int b    = blockIdx.x;     // 16
    int part = blockIdx.y;     // 32
    __shared__ float Qs[64 * 68];
    __shared__ float Ks[64 * 64];

    const float* Qb = qk + (size_t)b * (CC * N);
    const float* Kb = qk + (size_t)(16 + b) * (CC * N);
    int tid = threadIdx.x;
    int ti = tid >> 4, tj = tid & 15;
    int i0 = ti * 4, j0 = tj * 4;
    float accl[4][4] = {};

    for (int ci = 0; ci < 2; ++ci) {
        int n0 = (part * 2 + ci) * 64;
        if (ci) __syncthreads();           // previous compute done before restage
        for (int t = tid; t < 1024; t += 256) {
            int i = t >> 4, c4 = (t & 15) * 4;
            *(float4*)&Qs[i * 68 + c4] = *(const float4*)&Qb[(size_t)i * N + n0 + c4];
            *(float4*)&Ks[t * 4]       = *(const float4*)&Kb[(size_t)n0 * 64 + t * 4];
        }
        __syncthreads();
        for (int nn = 0; nn < 64; ++nn) {
            float4 kv = *reinterpret_cast<const float4*>(&Ks[nn * 64 + j0]);
            float qa[4];
#pragma unroll
            for (int a = 0; a < 4; ++a) qa[a] = Qs[(i0 + a) * 68 + nn];
#pragma unroll
            for (int a = 0; a < 4; ++a) {
                accl[a][0] = fmaf(qa[a], kv.x, accl[a][0]);
                accl[a][1] = fmaf(qa[a], kv.y, accl[a][1]);
                accl[a][2] = fmaf(qa[a], kv.z, accl[a][2]);
                accl[a][3] = fmaf(qa[a], kv.w, accl[a][3]);
            }
        }
    }
    float* So = Sp + ((size_t)part * 16 + b) * (CC * CC);
#pragma unroll
    for (int a = 0; a < 4; ++a) {
        float4 v = make_float4(accl[a][0], accl[a][1], accl[a][2], accl[a][3]);
        *(float4*)&So[(i0 + a) * 64 + j0] = v;
    }
}

// ---------------------------------------------------------------------------
// Reduce 32 logit partials, softmax over rows of S[b] (64x64), then fold Wo:
//   Mf[b][co][e] = sum_c Wo[co,c] * attn[c,e]  -> bf16, swizzled rows of 128B.
__global__ __launch_bounds__(256) void k_softmax_m(
    const float* __restrict__ Sp, const float* __restrict__ wot,
    ushortT* __restrict__ mf)
{
    int b = blockIdx.x, chunk = blockIdx.y;   // 16 x 8
    __shared__ float A[64 * 65];
    int tid = threadIdx.x;

    // stage = reduce 32 partials (float4 loads, L2-hot; scalar LDS stores keep
    // the 65-stride softmax banking conflict-free)
    for (int t = tid; t < 1024; t += 256) {
        int r = t >> 4, c4 = (t & 15) * 4;
        size_t base = (size_t)b * (CC * CC) + r * 64 + c4;
        float4 s = *(const float4*)&Sp[base];
#pragma unroll 8
        for (int p = 1; p < 32; ++p) {
            float4 v = *(const float4*)&Sp[(size_t)p * 16 * (CC * CC) + base];
            s.x += v.x; s.y += v.y; s.z += v.z; s.w += v.w;
        }
        A[r * 65 + c4 + 0] = s.x;
        A[r * 65 + c4 + 1] = s.y;
        A[r * 65 + c4 + 2] = s.z;
        A[r * 65 + c4 + 3] = s.w;
    }
    __syncthreads();
    if (tid < 64) {
        float mx = -1e30f;
        for (int j = 0; j < 64; ++j) mx = fmaxf(mx, A[tid * 65 + j]);
        float sum = 0.f;
        for (int j = 0; j < 64; ++j) {
            float e = __expf(A[tid * 65 + j] - mx);
            A[tid * 65 + j] = e;
            sum += e;
        }
        float inv = 1.f / sum;
        for (int j = 0; j < 64; ++j) A[tid * 65 + j] *= inv;
    }
    __syncthreads();

    int co = chunk * 64 + (tid & 63);
    int e0 = (tid >> 6) * 16;
    float acc[16] = {};
    for (int cc = 0; cc < 64; ++cc) {
        float w = wot[cc * C + co];
#pragma unroll
        for (int ee = 0; ee < 16; ++ee)
            acc[ee] = fmaf(w, A[cc * 65 + e0 + ee], acc[ee]);
    }
#pragma unroll
    for (int d = 0; d < 2; ++d) {
        int c = (e0 >> 3) + d;               // logical 8-elem chunk
        uintT p0 = (uintT)f2bf(acc[d * 8 + 0]) | ((uintT)f2bf(acc[d * 8 + 1]) << 16);
        uintT p1 = (uintT)f2bf(acc[d * 8 + 2]) | ((uintT)f2bf(acc[d * 8 + 3]) << 16);
        uintT p2 = (uintT)f2bf(acc[d * 8 + 4]) | ((uintT)f2bf(acc[d * 8 + 5]) << 16);
        uintT p3 = (uintT)f2bf(acc[d * 8 + 6]) | ((uintT)f2bf(acc[d * 8 + 7]) << 16);
        uint4 pk = make_uint4(p0, p1, p2, p3);
        size_t off = ((size_t)(b * C + co)) * 64 + (size_t)((c ^ (co & 7)) * 8);
        *(uint4*)&mf[off] = pk;
    }
}

// ---------------------------------------------------------------------------
// Output: out[b,co,n] = gamma*( sum_e Mf[co,e]*Vt[n,e] + bo[co] ) + x[b,co,n]
// MFMA with swapped operands: A-frag = Vt rows (n), B-frag = Mf rows (co).
// D rows = n -> each lane's 4 acc regs are 4 CONSECUTIVE n -> float4 epilogue.
__global__ __launch_bounds__(256) void k_out(
    const ushortT* __restrict__ vt, const ushortT* __restrict__ mf,
    const float* __restrict__ x, const float* __restrict__ bo,
    const float* __restrict__ gamma, float* __restrict__ out)
{
    __shared__ ushortT As[64 * 64];    // 8 KB  Mf rows co0..co0+64
    __shared__ ushortT Bs[256 * 64];   // 32 KB Vt rows n0..n0+256

    int b = blockIdx.x, ct = blockIdx.y, nt = blockIdx.z;
    int co0 = ct * 64, n0 = nt * 256;
    int tid = threadIdx.x;
    const char* asrc = (const char*)mf + ((size_t)(b * C + co0)) * 128;
    const char* bsrc = (const char*)vt + ((size_t)(b * N + n0)) * 128;
#pragma unroll
    for (int i = 0; i < 2; ++i) {
        int off = i * 4096 + tid * 16;
        GLL((char*)As + off, asrc + off);
    }
#pragma unroll
    for (int i = 0; i < 8; ++i) {
        int off = i * 4096 + tid * 16;
        GLL((char*)Bs + off, bsrc + off);
    }
    __syncthreads();

    int lane = tid & 63, wv = tid >> 6;
    int L15 = lane & 15, Lq = lane >> 4;
    float4v acc[4][4];                 // [n-frag][co-frag]
    const float4v vzero = {0.f, 0.f, 0.f, 0.f};
#pragma unroll
    for (int mi = 0; mi < 4; ++mi)
#pragma unroll
        for (int ni = 0; ni < 4; ++ni) acc[mi][ni] = vzero;

#pragma unroll
    for (int s = 0; s < 2; ++s) {
        short8 fa[4], fbm[4];
#pragma unroll
        for (int mi = 0; mi < 4; ++mi) {         // Vt frags (n rows)
            int row = wv * 64 + mi * 16 + L15;
            fa[mi] = *(const short8*)&Bs[row * 64 + ((4 * s + Lq) ^ (row & 7)) * 8];
        }
#pragma unroll
        for (int ni = 0; ni < 4; ++ni) {         // Mf frags (co rows)
            int rm = ni * 16 + L15;
            fbm[ni] = *(const short8*)&As[rm * 64 + ((4 * s + Lq) ^ (rm & 7)) * 8];
        }
#pragma unroll
        for (int mi = 0; mi < 4; ++mi)
#pragma unroll
            for (int ni = 0; ni < 4; ++ni)
                acc[mi][ni] = __builtin_amdgcn_mfma_f32_16x16x32_bf16(fa[mi], fbm[ni], acc[mi][ni], 0, 0, 0);
    }

    float g = gamma[0];
#pragma unroll
    for (int ni = 0; ni < 4; ++ni) {
        int co = co0 + ni * 16 + L15;
        float bov = bo[co];
#pragma unroll
        for (int mi = 0; mi < 4; ++mi) {
            int nbase = n0 + wv * 64 + mi * 16 + Lq * 4;
            size_t idx = ((size_t)(b * C + co)) * N + nbase;
            float4 xv = *(const float4*)&x[idx];
            float4v v4 = acc[mi][ni];
            float4 o;
            o.x = fmaf(g, v4[0] + bov, xv.x);
            o.y = fmaf(g, v4[1] + bov, xv.y);
            o.z = fmaf(g, v4[2] + bov, xv.z);
            o.w = fmaf(g, v4[3] + bov, xv.w);
            *(float4*)&out[idx] = o;
        }
    }
}

// ---------------------------------------------------------------------------
extern "C" void kernel_launch(void* const* d_in, const int* in_sizes, int n_in,
                              void* d_out, int out_size, void* d_ws, size_t ws_size,
                              hipStream_t stream)
{
    const float* x     = (const float*)d_in[0];
    const float* Wq    = (const float*)d_in[1];
    const float* bq    = (const float*)d_in[2];
    const float* Wk    = (const float*)d_in[3];
    const float* bk    = (const float*)d_in[4];
    const float* Wv    = (const float*)d_in[5];
    const float* bv    = (const float*)d_in[6];
    const float* Wo    = (const float*)d_in[7];
    const float* bo    = (const float*)d_in[8];
    const float* gamma = (const float*)d_in[9];

    float* ws   = (float*)d_ws;
    float* qk   = ws + QK_OFF;
    ushortT* vt = (ushortT*)(ws + VT_OFF);
    ushortT* mf = (ushortT*)(ws + MF_OFF);
    ushortT* wh = (ushortT*)(ws + WH_OFF);
    ushortT* wl = (ushortT*)(ws + WL_OFF);
    float* wot  = ws + WOT_OFF;
    float* Sp   = ws + SP_OFF;

    k_prep_w<<<512, 256, 0, stream>>>(Wq, Wk, Wv, Wo, wh, wl, wot);
    k_qkv<<<dim3(64, 16), 256, 0, stream>>>(x, wh, wl, bq, bk, bv, qk, vt);
    k_logits<<<dim3(16, 32), 256, 0, stream>>>(qk, Sp);
    k_softmax_m<<<dim3(16, 8), 256, 0, stream>>>(Sp, wot, mf);
    k_out<<<dim3(16, 8, 16), 256, 0, stream>>>(vt, mf, x, bo, gamma, (float*)d_out);
}